// Round 1
// baseline (742.434 us; speedup 1.0000x reference)
//
#include <hip/hip_runtime.h>

#define N_NODES 100000
#define N_EDGES 3200000
#define BATCH 16

// One thread per (edge, batch-column). 16 consecutive lanes share one edge:
// - weights/row/col are read once per 16-lane group (broadcast within the
//   coalesced transaction; a 64-lane wave touches 4 consecutive edges -> one
//   16B segment per index array per wave).
// - the y[col] gather is a fully-coalesced 64B segment per edge.
// - scatter is a fire-and-forget f32 atomicAdd (no sc0, no return wait).
__global__ void spmm_push_kernel(const float* __restrict__ y,
                                 const float* __restrict__ w,
                                 const int* __restrict__ row,
                                 const int* __restrict__ col,
                                 float* __restrict__ out) {
    long long tid = (long long)blockIdx.x * blockDim.x + threadIdx.x;
    const long long total = (long long)N_EDGES * BATCH;
    if (tid >= total) return;
    int e = (int)(tid >> 4);
    int b = (int)(tid & 15);
    int c = col[e];
    int r = row[e];
    float v = w[e] * y[(long long)c * BATCH + b];
    atomicAdd(&out[(long long)r * BATCH + b], v);
}

extern "C" void kernel_launch(void* const* d_in, const int* in_sizes, int n_in,
                              void* d_out, int out_size, void* d_ws, size_t ws_size,
                              hipStream_t stream) {
    const float* x   = (const float*)d_in[0];
    const float* w   = (const float*)d_in[1];
    const int*   row = (const int*)d_in[2];
    const int*   col = (const int*)d_in[3];
    float*       out = (float*)d_out;

    const size_t state_elems = (size_t)N_NODES * BATCH;      // 1.6M floats = 6.4MB
    float* buf_a = (float*)d_ws;
    float* buf_b = buf_a + state_elems;

    const long long total = (long long)N_EDGES * BATCH;      // 51.2M threads
    const int block = 256;
    const int grid = (int)((total + block - 1) / block);     // 200000 blocks

    // Layer 1: x -> buf_a
    hipMemsetAsync(buf_a, 0, state_elems * sizeof(float), stream);
    spmm_push_kernel<<<grid, block, 0, stream>>>(x, w, row, col, buf_a);

    // Layer 2: buf_a -> buf_b
    hipMemsetAsync(buf_b, 0, state_elems * sizeof(float), stream);
    spmm_push_kernel<<<grid, block, 0, stream>>>(buf_a, w, row, col, buf_b);

    // Layer 3: buf_b -> buf_a
    hipMemsetAsync(buf_a, 0, state_elems * sizeof(float), stream);
    spmm_push_kernel<<<grid, block, 0, stream>>>(buf_b, w, row, col, buf_a);

    // Layer 4: buf_a -> d_out
    hipMemsetAsync(d_out, 0, state_elems * sizeof(float), stream);
    spmm_push_kernel<<<grid, block, 0, stream>>>(buf_a, w, row, col, out);
}

// Round 3
// 661.289 us; speedup vs baseline: 1.1227x; 1.1227x over previous
//
#include <hip/hip_runtime.h>

#define N_NODES 100000
#define N_EDGES 3200000
#define BATCH 16
#define SCAN_CHUNK 1024
#define SCAN_BLOCKS ((N_NODES + SCAN_CHUNK - 1) / SCAN_CHUNK)   // 98

// ---------------- CSR build ----------------

__global__ void hist_kernel(const int* __restrict__ row, int* __restrict__ deg) {
    int e = blockIdx.x * blockDim.x + threadIdx.x;
    if (e < N_EDGES) atomicAdd(&deg[row[e]], 1);
}

// per-block (1024-element) sums of deg
__global__ void scan_block_sums(const int* __restrict__ deg, int* __restrict__ block_sums) {
    __shared__ int sdata[256];
    int base = blockIdx.x * SCAN_CHUNK;
    int t = threadIdx.x;
    int s = 0;
    for (int i = 0; i < 4; i++) {
        int idx = base + t + i * 256;
        s += (idx < N_NODES) ? deg[idx] : 0;
    }
    sdata[t] = s;
    __syncthreads();
    for (int off = 128; off > 0; off >>= 1) {
        if (t < off) sdata[t] += sdata[t + off];
        __syncthreads();
    }
    if (t == 0) block_sums[blockIdx.x] = sdata[0];
}

// serial exclusive scan of the 98 block sums; also sets row_ptr[N_NODES]
__global__ void scan_offsets(int* __restrict__ block_sums, int* __restrict__ row_ptr) {
    if (threadIdx.x == 0 && blockIdx.x == 0) {
        int acc = 0;
        for (int i = 0; i < SCAN_BLOCKS; i++) {
            int v = block_sums[i];
            block_sums[i] = acc;
            acc += v;
        }
        row_ptr[N_NODES] = N_EDGES;
    }
}

// final exclusive scan: row_ptr[i] for all i
__global__ void scan_final(const int* __restrict__ deg, const int* __restrict__ block_off,
                           int* __restrict__ row_ptr) {
    __shared__ int ssum[256];
    int base = blockIdx.x * SCAN_CHUNK;
    int t = threadIdx.x;
    int v[4];
    int s = 0;
    for (int i = 0; i < 4; i++) {
        int idx = base + 4 * t + i;
        v[i] = (idx < N_NODES) ? deg[idx] : 0;
        s += v[i];
    }
    ssum[t] = s;
    __syncthreads();
    // Hillis-Steele inclusive scan over thread sums
    for (int off = 1; off < 256; off <<= 1) {
        int x = (t >= off) ? ssum[t - off] : 0;
        __syncthreads();
        ssum[t] += x;
        __syncthreads();
    }
    int excl = block_off[blockIdx.x] + ssum[t] - s;
    for (int i = 0; i < 4; i++) {
        int idx = base + 4 * t + i;
        if (idx < N_NODES) row_ptr[idx] = excl;
        excl += v[i];
    }
}

// scatter (col, weight) pairs into CSR slots
__global__ void fill_kernel(const int* __restrict__ row, const int* __restrict__ col,
                            const float* __restrict__ w, const int* __restrict__ row_ptr,
                            int* __restrict__ cursor, int2* __restrict__ entries) {
    int e = blockIdx.x * blockDim.x + threadIdx.x;
    if (e >= N_EDGES) return;
    int r = row[e];
    int pos = row_ptr[r] + atomicAdd(&cursor[r], 1);
    entries[pos] = make_int2(col[e], __float_as_int(w[e]));
}

// ---------------- pull-SpMM layer ----------------
// 16 lanes per node (one per batch column). Entry load broadcasts within the
// 16-lane group; the y[col] gather is a coalesced 64B segment per edge.
// One plain 64B store per node -> zero atomics in the layer loop.
__global__ void pull_kernel(const float* __restrict__ y,
                            const int2* __restrict__ entries,
                            const int* __restrict__ row_ptr,
                            float* __restrict__ out) {
    int tid = blockIdx.x * blockDim.x + threadIdx.x;
    int node = tid >> 4;
    int b = tid & 15;
    if (node >= N_NODES) return;
    int beg = row_ptr[node];
    int end = row_ptr[node + 1];
    float acc = 0.f;
    int i = beg;
    for (; i + 1 < end; i += 2) {
        int2 e0 = entries[i];
        int2 e1 = entries[i + 1];
        acc += __int_as_float(e0.y) * y[e0.x * BATCH + b];
        acc += __int_as_float(e1.y) * y[e1.x * BATCH + b];
    }
    if (i < end) {
        int2 e0 = entries[i];
        acc += __int_as_float(e0.y) * y[e0.x * BATCH + b];
    }
    out[node * BATCH + b] = acc;
}

// ---------------- fallback: atomic push (round-1 validated, ~12.8MB ws) ----
__global__ void spmm_push_kernel(const float* __restrict__ y,
                                 const float* __restrict__ w,
                                 const int* __restrict__ row,
                                 const int* __restrict__ col,
                                 float* __restrict__ out) {
    long long tid = (long long)blockIdx.x * blockDim.x + threadIdx.x;
    const long long total = (long long)N_EDGES * BATCH;
    if (tid >= total) return;
    int e = (int)(tid >> 4);
    int b = (int)(tid & 15);
    float v = w[e] * y[(long long)col[e] * BATCH + b];
    atomicAdd(&out[(long long)row[e] * BATCH + b], v);
}

extern "C" void kernel_launch(void* const* d_in, const int* in_sizes, int n_in,
                              void* d_out, int out_size, void* d_ws, size_t ws_size,
                              hipStream_t stream) {
    const float* x   = (const float*)d_in[0];
    const float* w   = (const float*)d_in[1];
    const int*   row = (const int*)d_in[2];
    const int*   col = (const int*)d_in[3];
    float*       out = (float*)d_out;

    const size_t state_bytes = (size_t)N_NODES * BATCH * sizeof(float);  // 6.4 MB

    // CSR-path workspace requirement
    const size_t need_csr = (size_t)N_EDGES * sizeof(int2)       // entries 25.6 MB
                          + state_bytes                          // ping-pong buf
                          + (size_t)N_NODES * sizeof(int)        // deg
                          + (size_t)(N_NODES + 1) * sizeof(int)  // row_ptr
                          + (size_t)N_NODES * sizeof(int)        // cursor
                          + 128 * sizeof(int) + 256;             // block_sums + pad

    if (ws_size >= need_csr) {
        // ---- workspace carve-up ----
        char* p = (char*)d_ws;
        int2* entries   = (int2*)p;  p += (size_t)N_EDGES * sizeof(int2);
        float* buf      = (float*)p; p += state_bytes;
        int* deg        = (int*)p;   p += (size_t)N_NODES * sizeof(int);
        int* row_ptr    = (int*)p;   p += (size_t)(N_NODES + 1) * sizeof(int);
        int* cursor     = (int*)p;   p += (size_t)N_NODES * sizeof(int);
        int* block_sums = (int*)p;

        // ---- build CSR (once; reused by all 4 layers) ----
        hipMemsetAsync(deg, 0, N_NODES * sizeof(int), stream);
        hipMemsetAsync(cursor, 0, N_NODES * sizeof(int), stream);

        const int eblocks = (N_EDGES + 255) / 256;   // 12500
        hist_kernel<<<eblocks, 256, 0, stream>>>(row, deg);
        scan_block_sums<<<SCAN_BLOCKS, 256, 0, stream>>>(deg, block_sums);
        scan_offsets<<<1, 64, 0, stream>>>(block_sums, row_ptr);
        scan_final<<<SCAN_BLOCKS, 256, 0, stream>>>(deg, block_sums, row_ptr);
        fill_kernel<<<eblocks, 256, 0, stream>>>(row, col, w, row_ptr, cursor, entries);

        // ---- 4 pull layers; d_out doubles as ping-pong buffer ----
        const int nthreads = N_NODES * BATCH;        // 1.6M
        const int nblocks = (nthreads + 255) / 256;  // 6250
        pull_kernel<<<nblocks, 256, 0, stream>>>(x,   entries, row_ptr, buf);  // x   -> buf
        pull_kernel<<<nblocks, 256, 0, stream>>>(buf, entries, row_ptr, out);  // buf -> out
        pull_kernel<<<nblocks, 256, 0, stream>>>(out, entries, row_ptr, buf);  // out -> buf
        pull_kernel<<<nblocks, 256, 0, stream>>>(buf, entries, row_ptr, out);  // buf -> out
    } else {
        // ---- fallback: validated atomic-push path (needs 2 state buffers) ----
        float* buf_a = (float*)d_ws;
        float* buf_b = buf_a + (size_t)N_NODES * BATCH;

        const long long total = (long long)N_EDGES * BATCH;
        const int block = 256;
        const int grid = (int)((total + block - 1) / block);

        hipMemsetAsync(buf_a, 0, state_bytes, stream);
        spmm_push_kernel<<<grid, block, 0, stream>>>(x, w, row, col, buf_a);
        hipMemsetAsync(buf_b, 0, state_bytes, stream);
        spmm_push_kernel<<<grid, block, 0, stream>>>(buf_a, w, row, col, buf_b);
        hipMemsetAsync(buf_a, 0, state_bytes, stream);
        spmm_push_kernel<<<grid, block, 0, stream>>>(buf_b, w, row, col, buf_a);
        hipMemsetAsync(d_out, 0, state_bytes, stream);
        spmm_push_kernel<<<grid, block, 0, stream>>>(buf_a, w, row, col, out);
    }
}